// Round 13
// baseline (733.869 us; speedup 1.0000x reference)
//
#include <hip/hip_runtime.h>

// VectorQuantizer: bf16-MFMA approximate distance pass + margin shortlist +
// exact f32 rescore + gather/losses.  N=32768 rows, D=256, K=8192 codes.
//
// R13: NO LDS staging for B. e16 is stored FRAGMENT-MAJOR so a wave's
// B-fragment load is one coalesced 1KB global_load_dwordx4 served from L2
// (e16 = 4MB, fits per-XCD L2). Kills: per-chunk barriers + vmcnt(0)
// drains (the ~20%-MfmaUtil wall of R5/R7/R8), all LDS reads, all bank
// conflicts. zi=4 row-tiles in registers (ratio: 4 MFMA per B-load).
// VGPR envelope: the ONLY >128-VGPR config observed is R6's (256 thr,
// hint-free launch_bounds, big LDS) -> replicate: 64KB volatile-anchored
// LDS pad (2 blocks/CU), no waves_per_eu, no 2nd launch_bounds arg.
// Numerics: identical bf16 values + (s,lg) pairing as R12 -> identical
// MFMA results -> R12-verified epilogue/append/rescore kept verbatim.

#define NROWS 32768
#define NE    8192
#define DDIM  256
#define BM    64            // rows/block = zi(4) x 16
#define CAP   64
#define MARGIN 1e-4f
#define NCH   (NE / 64)     // 128 chunks of 64 candidates

typedef __attribute__((ext_vector_type(8))) short bf16x8;
typedef __attribute__((ext_vector_type(4))) float f32x4;
typedef unsigned short u16;

__device__ __forceinline__ u16 f2bf(float f) {
  unsigned x = __float_as_uint(f);
  return (u16)((x + 0x7fffu + ((x >> 16) & 1u)) >> 16);   // RNE
}

// ---------------- row norms: a[n] = sum z^2, c[k] = sum e^2 -------------
__global__ __launch_bounds__(256)
void vq_norms(const float* __restrict__ z, const float* __restrict__ emb,
              float* __restrict__ arow, float* __restrict__ cemb) {
  int gid  = blockIdx.x * 256 + threadIdx.x;
  int wid  = gid >> 6;
  int lane = threadIdx.x & 63;
  const float* src;
  float* dst;
  if (wid < NROWS) { src = z + (size_t)wid * DDIM;   dst = arow + wid; }
  else             { int r = wid - NROWS;
                     src = emb + (size_t)r * DDIM;   dst = cemb + r; }
  float4 v = *reinterpret_cast<const float4*>(src + lane * 4);
  float s = v.x * v.x + v.y * v.y;
  s += v.z * v.z;
  s += v.w * v.w;
  #pragma unroll
  for (int off = 1; off < 64; off <<= 1) s += __shfl_xor(s, off, 64);
  if (lane == 0) *dst = s;
}

// -------- emb f32 -> bf16, FRAGMENT-MAJOR for direct global B-loads -----
// 16B-chunk o encodes: g16 = o>>9 (16-cand group), s = (o>>6)&7 (k-tile),
// lane l = o&63 with lg=l>>4, l15=l&15. Chunk holds cand (g16*16+l15),
// k-range [(s*4+lg)*8, +8). A wave's fragment (g16,s) = 64 consecutive
// chunks = 1KB contiguous.
__global__ __launch_bounds__(256)
void vq_cvt(const float* __restrict__ emb, u16* __restrict__ e16) {
  int o   = blockIdx.x * 256 + threadIdx.x;   // 0 .. NE*32-1
  int g16 = o >> 9;
  int r   = o & 511;
  int s   = r >> 6;
  int l   = r & 63;
  int lg  = l >> 4, l15 = l & 15;
  int c   = g16 * 16 + l15;
  int kc  = s * 4 + lg;
  const float* src = emb + (size_t)c * DDIM + kc * 8;
  float4 v0 = *reinterpret_cast<const float4*>(src);
  float4 v1 = *reinterpret_cast<const float4*>(src + 4);
  u16 ov[8] = {f2bf(v0.x), f2bf(v0.y), f2bf(v0.z), f2bf(v0.w),
               f2bf(v1.x), f2bf(v1.y), f2bf(v1.z), f2bf(v1.w)};
  *reinterpret_cast<bf16x8*>(e16 + (size_t)o * 8) =
      *reinterpret_cast<bf16x8*>(ov);
}

// ---------------- MFMA approx pass + shortlist (barrier-free) -----------
// 4 waves = 4 wn 16-cand groups; zi=4 row-tiles (64 rows/block).
// Per chunk: 8 coalesced 1KB B-fragment loads from L2, 32 MFMAs.
__global__ __launch_bounds__(256)
void vq_mfma(const float* __restrict__ z, const u16* __restrict__ e16,
             const float* __restrict__ arow, const float* __restrict__ cemb,
             unsigned* __restrict__ cnt, int* __restrict__ list) {
  // Occupancy governor (R6 envelope): 64KB -> 2 blocks/CU; volatile anchor
  // keeps it allocated. No LDS data path otherwise.
  __shared__ char pad[65536];
  if (threadIdx.x == 0) ((volatile char*)pad)[0] = 0;

  const int t    = threadIdx.x;
  const int R0   = blockIdx.x * BM;
  const int lane = t & 63;
  const int wn   = t >> 6;          // 0..3 : 16-cand group
  const int l15  = lane & 15;
  const int lg   = lane >> 4;       // 0..3

  // ---- A fragments: 4 row-tiles straight from global z, in registers ----
  bf16x8 af[4][8];
  float  a_r[4], runmin[4];
  #pragma unroll
  for (int zi = 0; zi < 4; ++zi) {
    const int row = R0 + zi * 16 + l15;
    const float* zr = z + (size_t)row * DDIM;
    #pragma unroll
    for (int s = 0; s < 8; ++s) {
      const float* src = zr + (s * 4 + lg) * 8;
      float4 v0 = *reinterpret_cast<const float4*>(src);
      float4 v1 = *reinterpret_cast<const float4*>(src + 4);
      u16 o[8] = {f2bf(v0.x), f2bf(v0.y), f2bf(v0.z), f2bf(v0.w),
                  f2bf(v1.x), f2bf(v1.y), f2bf(v1.z), f2bf(v1.w)};
      af[zi][s] = *reinterpret_cast<bf16x8*>(o);
    }
    a_r[zi] = arow[row];
    runmin[zi] = 3.4e38f;
  }

  for (int ch = 0; ch < NCH; ++ch) {
    const int C0  = ch * 64;
    const int g16 = ch * 4 + wn;

    // ---- issue all 8 B-fragment loads (coalesced 1KB each, L2-hot) ----
    bf16x8 bfr[8];
    #pragma unroll
    for (int s = 0; s < 8; ++s)
      bfr[s] = *reinterpret_cast<const bf16x8*>(
          e16 + ((size_t)(g16 * 8 + s) * 64 + lane) * 8);

    const float4 cvv = *reinterpret_cast<const float4*>(
        &cemb[C0 + wn * 16 + lg * 4]);

    // ---- compute: acc[zi] = mfma(B-frag, A-frag) (swapped operands) ----
    f32x4 acc[4];
    #pragma unroll
    for (int zi = 0; zi < 4; ++zi) acc[zi] = (f32x4){0.f, 0.f, 0.f, 0.f};
    #pragma unroll
    for (int s = 0; s < 8; ++s)
      #pragma unroll
      for (int zi = 0; zi < 4; ++zi)
        acc[zi] = __builtin_amdgcn_mfma_f32_16x16x32_bf16(
            bfr[s], af[zi][s], acc[zi], 0, 0, 0);

    // ---- epilogue (R12-verified): row mins, 2 shuffles, u-form appends --
    // lane's z-row (zi) = R0 + zi*16 + l15
    // lane's cand (r)   = C0 + wn*16 + lg*4 + r
    #pragma unroll
    for (int zi = 0; zi < 4; ++zi) {
      float lm = 3.4e38f;
      #pragma unroll
      for (int r = 0; r < 4; ++r) {
        float dd = fmaf(-2.0f, acc[zi][r], a_r[zi]) + cvv[r];
        lm = fminf(lm, dd);
      }
      float gm = fminf(lm, __shfl_xor(lm, 16, 64));
      gm = fminf(gm, __shfl_xor(gm, 32, 64));
      runmin[zi] = fminf(runmin[zi], gm);
      float thr = runmin[zi] + MARGIN;
      if (lm <= thr) {
        // u-form test (R5-verified): d<=thr <=> u >= 0.5*(a+c-thr)
        const int rowg = R0 + zi * 16 + l15;
        const float h = 0.5f * (a_r[zi] - thr);
        #pragma unroll
        for (int r = 0; r < 4; ++r)
          if (acc[zi][r] >= fmaf(0.5f, cvv[r], h)) {
            int k = C0 + wn * 16 + lg * 4 + r;
            unsigned p = atomicAdd(&cnt[rowg], 1u);
            if (p < CAP) list[(size_t)rowg * CAP + p] = k;
          }
      }
    }
  }
}

// ---------------- exact f32 rescore of shortlists -----------------------
__global__ __launch_bounds__(256)
void vq_rescore(const float* __restrict__ z, const float* __restrict__ emb,
                const float* __restrict__ arow, const float* __restrict__ cemb,
                const unsigned* __restrict__ cnt, const int* __restrict__ list,
                int* __restrict__ ws_idx) {
  const int row  = blockIdx.x * 4 + (threadIdx.x >> 6);
  const int lane = threadIdx.x & 63;
  const float a  = arow[row];
  const float4 zv = *reinterpret_cast<const float4*>(
      z + (size_t)row * DDIM + lane * 4);
  unsigned n = cnt[row];
  float bd = 3.4e38f;
  int   bk = 0;

  const bool fullscan = (n == 0 || n > CAP);
  const int  m = fullscan ? NE : (int)n;
  for (int i = 0; i < m; ++i) {
    int k = fullscan ? i : list[(size_t)row * CAP + i];
    const float4 ev = *reinterpret_cast<const float4*>(
        emb + (size_t)k * DDIM + lane * 4);
    float p = zv.x * ev.x;
    p = fmaf(zv.y, ev.y, p);
    p = fmaf(zv.z, ev.z, p);
    p = fmaf(zv.w, ev.w, p);
    #pragma unroll
    for (int off = 1; off < 64; off <<= 1) p += __shfl_xor(p, off, 64);
    float d = fmaf(-2.0f, p, a) + cemb[k];   // exact ref chain
    if (d < bd || (d == bd && k < bk)) { bd = d; bk = k; }
  }
  if (lane == 0) ws_idx[row] = bk;
}

// ---------------- gather + STE + losses ---------------------------------
__global__ __launch_bounds__(256)
void vq_gather(const float* __restrict__ z, const float* __restrict__ emb,
               const int* __restrict__ ws_idx,
               float* __restrict__ out_zq, float* __restrict__ out_idx,
               double* __restrict__ loss_accum) {
  __shared__ float part[4];
  const int t  = threadIdx.x;
  const int R0 = blockIdx.x * 128;
  float lsum = 0.0f;
  for (int rr = 0; rr < 128; ++rr) {
    const int kb = ws_idx[R0 + rr];
    const size_t gi = (size_t)(R0 + rr) * DDIM + t;
    const float zv = z[gi];
    const float qv = emb[(size_t)kb * DDIM + t];
    const float diff = qv - zv;              // z_q - z
    out_zq[gi] = zv + diff;                  // z + (z_q - z) exact chain
    lsum = fmaf(diff, diff, lsum);
  }
  #pragma unroll
  for (int off = 1; off < 64; off <<= 1) lsum += __shfl_xor(lsum, off, 64);
  if ((t & 63) == 0) part[t >> 6] = lsum;
  __syncthreads();
  if (t == 0) {
    float tot = (part[0] + part[1]) + (part[2] + part[3]);
    atomicAdd(loss_accum, (double)tot);
  }
  if (t < 128) out_idx[R0 + t] = (float)ws_idx[R0 + t];
}

// ---------------- scalar losses -----------------------------------------
__global__ void vq_finalize(const double* __restrict__ loss_accum,
                            float* __restrict__ out_losses) {
  double m = *loss_accum / (double)((size_t)NROWS * DDIM);
  out_losses[0] = (float)(0.25 * m);   // loss_commit = BETA * mse
  out_losses[1] = (float)m;            // loss_codebook
}

extern "C" void kernel_launch(void* const* d_in, const int* in_sizes, int n_in,
                              void* d_out, int out_size, void* d_ws, size_t ws_size,
                              hipStream_t stream) {
  const float* z   = (const float*)d_in[0];
  const float* emb = (const float*)d_in[1];
  float* out        = (float*)d_out;
  float* out_zq     = out;                            // [8388608]
  float* out_losses = out + (size_t)NROWS * DDIM;     // [2]
  float* out_idx    = out + (size_t)NROWS * DDIM + 2; // [32768] as f32

  // persistent ws scratch (small)
  double* loss_accum = (double*)d_ws;
  float*  arow   = (float*)((char*)d_ws + 256);
  float*  cemb   = arow + NROWS;
  int*    ws_idx = (int*)(cemb + NE);

  // large scratch carved from d_out's z_q region (fully rewritten each call;
  // vq_gather overwrites after all readers are done => deterministic)
  u16*      e16  = (u16*)d_out;                              // [0, 4MB)
  int*      list = (int*)((char*)d_out + (4 << 20));         // [4MB, 12MB) CAP=64
  unsigned* cnt  = (unsigned*)((char*)d_out + (12 << 20));   // [12MB, +128KB)

  hipMemsetAsync(d_ws, 0, 8, stream);
  hipMemsetAsync(cnt, 0, NROWS * sizeof(unsigned), stream);
  vq_norms<<<(NROWS + NE) / 4, 256, 0, stream>>>(z, emb, arow, cemb);
  vq_cvt<<<NE * 32 / 256, 256, 0, stream>>>(emb, e16);
  vq_mfma<<<NROWS / BM, 256, 0, stream>>>(z, e16, arow, cemb, cnt, list);
  vq_rescore<<<NROWS / 4, 256, 0, stream>>>(z, emb, arow, cemb, cnt, list, ws_idx);
  vq_gather<<<NROWS / 128, 256, 0, stream>>>(z, emb, ws_idx,
                                             out_zq, out_idx, loss_accum);
  vq_finalize<<<1, 1, 0, stream>>>(loss_accum, out_losses);
}

// Round 14
// 592.330 us; speedup vs baseline: 1.2390x; 1.2390x over previous
//
#include <hip/hip_runtime.h>

// VectorQuantizer: bf16-MFMA approximate distance pass + margin shortlist +
// exact f32 rescore + gather/losses.  N=32768 rows, D=256, K=8192 codes.
//
// R14 = R8's proven double-buffered schedule + R13's fragment-major layout
// + zi=2.  R8's counters showed 1025 conflict-cyc/chunk/CU: row-major Bs
// puts all 16 l15-lanes on bank 0 (512B row stride); the lg-groups then
// collide 4-way. Fragment-major fixes it: a wave's B-fragment is ONE
// contiguous 1KB LDS region (lane*16) -> optimal bank schedule, and
// global_load_lds writes the identical linear pattern (no swizzle at all).
// zi=2 (af[2][8]=64 VGPR, total ~105 < 128-cap, no spill) doubles the
// MFMA:LDS-read ratio. 8 waves = wm(2 x 32-row) x wn(4 x 16-cand), ci=1.
// Epilogue/append/rescore = R12/R13-verified numerics, CAP=64.

#define NROWS 32768
#define NE    8192
#define DDIM  256
#define BM    64
#define CAP   64
#define MARGIN 1e-4f
#define NCH   (NE / 64)    // 128 chunks of 64 candidates

typedef __attribute__((ext_vector_type(8))) short bf16x8;
typedef __attribute__((ext_vector_type(4))) float f32x4;
typedef unsigned short u16;

__device__ __forceinline__ u16 f2bf(float f) {
  unsigned x = __float_as_uint(f);
  return (u16)((x + 0x7fffu + ((x >> 16) & 1u)) >> 16);   // RNE
}

__device__ __forceinline__ void gload_lds16(const void* g, void* l) {
  __builtin_amdgcn_global_load_lds(
      (const __attribute__((address_space(1))) void*)g,
      (__attribute__((address_space(3))) void*)l, 16, 0, 0);
}

// ---------------- row norms: a[n] = sum z^2, c[k] = sum e^2 -------------
__global__ __launch_bounds__(256)
void vq_norms(const float* __restrict__ z, const float* __restrict__ emb,
              float* __restrict__ arow, float* __restrict__ cemb) {
  int gid  = blockIdx.x * 256 + threadIdx.x;
  int wid  = gid >> 6;
  int lane = threadIdx.x & 63;
  const float* src;
  float* dst;
  if (wid < NROWS) { src = z + (size_t)wid * DDIM;   dst = arow + wid; }
  else             { int r = wid - NROWS;
                     src = emb + (size_t)r * DDIM;   dst = cemb + r; }
  float4 v = *reinterpret_cast<const float4*>(src + lane * 4);
  float s = v.x * v.x + v.y * v.y;
  s += v.z * v.z;
  s += v.w * v.w;
  #pragma unroll
  for (int off = 1; off < 64; off <<= 1) s += __shfl_xor(s, off, 64);
  if (lane == 0) *dst = s;
}

// -------- emb f32 -> bf16, FRAGMENT-MAJOR (R13-verified layout) ---------
// 16B-chunk o: g16 = o>>9 (16-cand group), s = (o>>6)&7 (k-tile),
// lane l = o&63 (lg=l>>4, l15=l&15). Chunk holds cand (g16*16+l15),
// k-range [(s*4+lg)*8, +8). Fragment (g16,s) = 1KB contiguous.
// Candidate-chunk ch (64 cands) = g16 in [4ch,4ch+4) = 32KB contiguous.
__global__ __launch_bounds__(256)
void vq_cvt(const float* __restrict__ emb, u16* __restrict__ e16) {
  int o   = blockIdx.x * 256 + threadIdx.x;   // 0 .. NE*32-1
  int g16 = o >> 9;
  int r   = o & 511;
  int s   = r >> 6;
  int l   = r & 63;
  int lg  = l >> 4, l15 = l & 15;
  int c   = g16 * 16 + l15;
  int kc  = s * 4 + lg;
  const float* src = emb + (size_t)c * DDIM + kc * 8;
  float4 v0 = *reinterpret_cast<const float4*>(src);
  float4 v1 = *reinterpret_cast<const float4*>(src + 4);
  u16 ov[8] = {f2bf(v0.x), f2bf(v0.y), f2bf(v0.z), f2bf(v0.w),
               f2bf(v1.x), f2bf(v1.y), f2bf(v1.z), f2bf(v1.w)};
  *reinterpret_cast<bf16x8*>(e16 + (size_t)o * 8) =
      *reinterpret_cast<bf16x8*>(ov);
}

// ---------------- MFMA approx pass + shortlist --------------------------
// 8 waves: wm=wid>>2 (2 x 32-row half, zi=2), wn=wid&3 (4 x 16-cand qtr).
// Swapped operands mfma(bfr, af): lane holds 4 cands of z-row (zi,l15).
__global__ __launch_bounds__(512)
void vq_mfma(const float* __restrict__ z, const u16* __restrict__ e16,
             const float* __restrict__ arow, const float* __restrict__ cemb,
             unsigned* __restrict__ cnt, int* __restrict__ list) {
  __shared__ u16 Bs[2][64 * DDIM];   // 2 x 32 KB, fragment-major

  const int t    = threadIdx.x;
  const int R0   = blockIdx.x * BM;
  const int lane = t & 63;
  const int wid  = t >> 6;          // 0..7
  const int wm   = wid >> 2;        // 0..1 : 32-row half
  const int wn   = wid & 3;         // 0..3 : 16-cand quarter
  const int l15  = lane & 15;
  const int lg   = lane >> 4;       // 0..3

  // ---- A fragments: 2 row-tiles straight from global z, in registers ----
  // af[zi][s] = z-row (R0+wm*32+zi*16+l15), global k-chunk (s*4+lg)*8..+8
  bf16x8 af[2][8];
  float  a_r[2], runmin[2];
  #pragma unroll
  for (int zi = 0; zi < 2; ++zi) {
    const int row = R0 + wm * 32 + zi * 16 + l15;
    const float* zr = z + (size_t)row * DDIM;
    #pragma unroll
    for (int s = 0; s < 8; ++s) {
      const float* src = zr + (s * 4 + lg) * 8;
      float4 v0 = *reinterpret_cast<const float4*>(src);
      float4 v1 = *reinterpret_cast<const float4*>(src + 4);
      u16 o[8] = {f2bf(v0.x), f2bf(v0.y), f2bf(v0.z), f2bf(v0.w),
                  f2bf(v1.x), f2bf(v1.y), f2bf(v1.z), f2bf(v1.w)};
      af[zi][s] = *reinterpret_cast<bf16x8*>(o);
    }
    a_r[zi] = arow[row];
    runmin[zi] = 3.4e38f;
  }

  // ---- prologue: DMA chunk 0 -> Bs[0] (32 frags x 1KB; wave stages 4) ----
  {
    const char* src = (const char*)e16;
    #pragma unroll
    for (int i = 0; i < 4; ++i) {
      int f = wid * 4 + i;
      gload_lds16(src + f * 1024 + lane * 16, (char*)&Bs[0][0] + f * 1024);
    }
  }
  __syncthreads();   // drains prologue DMA

  for (int ch = 0; ch < NCH; ++ch) {
    const int buf = ch & 1;
    const int C0  = ch * 64;

    // ---- issue next chunk's DMA first (whole chunk to land) ----
    if (ch + 1 < NCH) {
      const char* src = (const char*)e16 + (size_t)(ch + 1) * 32768;
      char* dst = (char*)&Bs[buf ^ 1][0];
      #pragma unroll
      for (int i = 0; i < 4; ++i) {
        int f = wid * 4 + i;
        gload_lds16(src + f * 1024 + lane * 16, dst + f * 1024);
      }
    }

    // ---- hoisted epilogue constants (L2 latency hides under MFMAs) ----
    const float4 cvv = *reinterpret_cast<const float4*>(
        &cemb[C0 + wn * 16 + lg * 4]);

    // ---- compute: contiguous 1KB fragment reads, 16 MFMAs ----
    f32x4 acc[2];
    acc[0] = (f32x4){0.f, 0.f, 0.f, 0.f};
    acc[1] = (f32x4){0.f, 0.f, 0.f, 0.f};

    const u16* Bp = &Bs[buf][0];
    #pragma unroll
    for (int s = 0; s < 8; ++s) {
      // fragment (wn, s): byte ofs (wn*8+s)*1024 + lane*16  (conflict-free)
      const bf16x8 bfr = *reinterpret_cast<const bf16x8*>(
          &Bp[(wn * 8 + s) * 512 + lane * 8]);
      #pragma unroll
      for (int zi = 0; zi < 2; ++zi)
        acc[zi] = __builtin_amdgcn_mfma_f32_16x16x32_bf16(
            bfr, af[zi][s], acc[zi], 0, 0, 0);
    }

    // ---- epilogue (R12/R13-verified): row mins, 2 shuffles, appends ----
    // lane's z-row (zi) = R0 + wm*32 + zi*16 + l15
    // lane's cand (r)   = C0 + wn*16 + lg*4 + r
    #pragma unroll
    for (int zi = 0; zi < 2; ++zi) {
      float lm = 3.4e38f;
      #pragma unroll
      for (int r = 0; r < 4; ++r) {
        float dd = fmaf(-2.0f, acc[zi][r], a_r[zi]) + cvv[r];
        lm = fminf(lm, dd);
      }
      float gm = fminf(lm, __shfl_xor(lm, 16, 64));
      gm = fminf(gm, __shfl_xor(gm, 32, 64));
      runmin[zi] = fminf(runmin[zi], gm);
      float thr = runmin[zi] + MARGIN;
      if (lm <= thr) {
        // u-form test (R5-verified): d<=thr <=> u >= 0.5*(a+c-thr)
        const int rowg = R0 + wm * 32 + zi * 16 + l15;
        const float h = 0.5f * (a_r[zi] - thr);
        #pragma unroll
        for (int r = 0; r < 4; ++r)
          if (acc[zi][r] >= fmaf(0.5f, cvv[r], h)) {
            int k = C0 + wn * 16 + lg * 4 + r;
            unsigned p = atomicAdd(&cnt[rowg], 1u);
            if (p < CAP) list[(size_t)rowg * CAP + p] = k;
          }
      }
    }

    __syncthreads();   // drains this chunk's reads + next chunk's DMA
  }
}

// ---------------- exact f32 rescore of shortlists -----------------------
__global__ __launch_bounds__(256)
void vq_rescore(const float* __restrict__ z, const float* __restrict__ emb,
                const float* __restrict__ arow, const float* __restrict__ cemb,
                const unsigned* __restrict__ cnt, const int* __restrict__ list,
                int* __restrict__ ws_idx) {
  const int row  = blockIdx.x * 4 + (threadIdx.x >> 6);
  const int lane = threadIdx.x & 63;
  const float a  = arow[row];
  const float4 zv = *reinterpret_cast<const float4*>(
      z + (size_t)row * DDIM + lane * 4);
  unsigned n = cnt[row];
  float bd = 3.4e38f;
  int   bk = 0;

  const bool fullscan = (n == 0 || n > CAP);
  const int  m = fullscan ? NE : (int)n;
  for (int i = 0; i < m; ++i) {
    int k = fullscan ? i : list[(size_t)row * CAP + i];
    const float4 ev = *reinterpret_cast<const float4*>(
        emb + (size_t)k * DDIM + lane * 4);
    float p = zv.x * ev.x;
    p = fmaf(zv.y, ev.y, p);
    p = fmaf(zv.z, ev.z, p);
    p = fmaf(zv.w, ev.w, p);
    #pragma unroll
    for (int off = 1; off < 64; off <<= 1) p += __shfl_xor(p, off, 64);
    float d = fmaf(-2.0f, p, a) + cemb[k];   // exact ref chain
    if (d < bd || (d == bd && k < bk)) { bd = d; bk = k; }
  }
  if (lane == 0) ws_idx[row] = bk;
}

// ---------------- gather + STE + losses ---------------------------------
__global__ __launch_bounds__(256)
void vq_gather(const float* __restrict__ z, const float* __restrict__ emb,
               const int* __restrict__ ws_idx,
               float* __restrict__ out_zq, float* __restrict__ out_idx,
               double* __restrict__ loss_accum) {
  __shared__ float part[4];
  const int t  = threadIdx.x;
  const int R0 = blockIdx.x * 128;
  float lsum = 0.0f;
  for (int rr = 0; rr < 128; ++rr) {
    const int kb = ws_idx[R0 + rr];
    const size_t gi = (size_t)(R0 + rr) * DDIM + t;
    const float zv = z[gi];
    const float qv = emb[(size_t)kb * DDIM + t];
    const float diff = qv - zv;              // z_q - z
    out_zq[gi] = zv + diff;                  // z + (z_q - z) exact chain
    lsum = fmaf(diff, diff, lsum);
  }
  #pragma unroll
  for (int off = 1; off < 64; off <<= 1) lsum += __shfl_xor(lsum, off, 64);
  if ((t & 63) == 0) part[t >> 6] = lsum;
  __syncthreads();
  if (t == 0) {
    float tot = (part[0] + part[1]) + (part[2] + part[3]);
    atomicAdd(loss_accum, (double)tot);
  }
  if (t < 128) out_idx[R0 + t] = (float)ws_idx[R0 + t];
}

// ---------------- scalar losses -----------------------------------------
__global__ void vq_finalize(const double* __restrict__ loss_accum,
                            float* __restrict__ out_losses) {
  double m = *loss_accum / (double)((size_t)NROWS * DDIM);
  out_losses[0] = (float)(0.25 * m);   // loss_commit = BETA * mse
  out_losses[1] = (float)m;            // loss_codebook
}

extern "C" void kernel_launch(void* const* d_in, const int* in_sizes, int n_in,
                              void* d_out, int out_size, void* d_ws, size_t ws_size,
                              hipStream_t stream) {
  const float* z   = (const float*)d_in[0];
  const float* emb = (const float*)d_in[1];
  float* out        = (float*)d_out;
  float* out_zq     = out;                            // [8388608]
  float* out_losses = out + (size_t)NROWS * DDIM;     // [2]
  float* out_idx    = out + (size_t)NROWS * DDIM + 2; // [32768] as f32

  // persistent ws scratch (small)
  double* loss_accum = (double*)d_ws;
  float*  arow   = (float*)((char*)d_ws + 256);
  float*  cemb   = arow + NROWS;
  int*    ws_idx = (int*)(cemb + NE);

  // large scratch carved from d_out's z_q region (fully rewritten each call;
  // vq_gather overwrites after all readers are done => deterministic)
  u16*      e16  = (u16*)d_out;                              // [0, 4MB)
  int*      list = (int*)((char*)d_out + (4 << 20));         // [4MB, 12MB) CAP=64
  unsigned* cnt  = (unsigned*)((char*)d_out + (12 << 20));   // [12MB, +128KB)

  hipMemsetAsync(d_ws, 0, 8, stream);
  hipMemsetAsync(cnt, 0, NROWS * sizeof(unsigned), stream);
  vq_norms<<<(NROWS + NE) / 4, 256, 0, stream>>>(z, emb, arow, cemb);
  vq_cvt<<<NE * 32 / 256, 256, 0, stream>>>(emb, e16);
  vq_mfma<<<NROWS / BM, 512, 0, stream>>>(z, e16, arow, cemb, cnt, list);
  vq_rescore<<<NROWS / 4, 256, 0, stream>>>(z, emb, arow, cemb, cnt, list, ws_idx);
  vq_gather<<<NROWS / 128, 256, 0, stream>>>(z, emb, ws_idx,
                                             out_zq, out_idx, loss_accum);
  vq_finalize<<<1, 1, 0, stream>>>(loss_accum, out_losses);
}

// Round 15
// 333.723 us; speedup vs baseline: 2.1990x; 1.7749x over previous
//
#include <hip/hip_runtime.h>

// VectorQuantizer: bf16-MFMA approximate distance pass + margin shortlist +
// exact f32 rescore + gather/losses.  N=32768 rows, D=256, K=8192 codes.
//
// R15 = R8 (proven best: 276us vq_mfma, VGPR 52, 2 blk/CU, 42% occ)
//       + R14's fragment-major conflict-free LDS layout (proven: 0 conflicts,
//         absmax 0). ONE delta from R8; tiling/schedule/occupancy untouched.
// R14's lesson: zi=2 -> VGPR 84 -> 1 blk/CU (2-blk placement needs VGPR<~64
// at 512thr) -> lost cross-block desync. So zi stays 1.
// Fragment-major: frag (g16,s) = 1KB contiguous; lane reads +lane*16 ->
// optimal bank schedule, DMA dest same linear pattern, no swizzle anywhere.

#define NROWS 32768
#define NE    8192
#define DDIM  256
#define BM    64
#define CAP   64
#define MARGIN 1e-4f
#define NCH   (NE / 64)    // 128 chunks of 64 candidates

typedef __attribute__((ext_vector_type(8))) short bf16x8;
typedef __attribute__((ext_vector_type(4))) float f32x4;
typedef unsigned short u16;

__device__ __forceinline__ u16 f2bf(float f) {
  unsigned x = __float_as_uint(f);
  return (u16)((x + 0x7fffu + ((x >> 16) & 1u)) >> 16);   // RNE
}

__device__ __forceinline__ void gload_lds16(const void* g, void* l) {
  __builtin_amdgcn_global_load_lds(
      (const __attribute__((address_space(1))) void*)g,
      (__attribute__((address_space(3))) void*)l, 16, 0, 0);
}

// ---------------- row norms: a[n] = sum z^2, c[k] = sum e^2 -------------
__global__ __launch_bounds__(256)
void vq_norms(const float* __restrict__ z, const float* __restrict__ emb,
              float* __restrict__ arow, float* __restrict__ cemb) {
  int gid  = blockIdx.x * 256 + threadIdx.x;
  int wid  = gid >> 6;
  int lane = threadIdx.x & 63;
  const float* src;
  float* dst;
  if (wid < NROWS) { src = z + (size_t)wid * DDIM;   dst = arow + wid; }
  else             { int r = wid - NROWS;
                     src = emb + (size_t)r * DDIM;   dst = cemb + r; }
  float4 v = *reinterpret_cast<const float4*>(src + lane * 4);
  float s = v.x * v.x + v.y * v.y;
  s += v.z * v.z;
  s += v.w * v.w;
  #pragma unroll
  for (int off = 1; off < 64; off <<= 1) s += __shfl_xor(s, off, 64);
  if (lane == 0) *dst = s;
}

// -------- emb f32 -> bf16, FRAGMENT-MAJOR (R13/R14-verified layout) -----
// 16B-chunk o: g16 = o>>9 (16-cand group), s = (o>>6)&7 (k-tile),
// lane l = o&63 (lg=l>>4, l15=l&15). Chunk holds cand (g16*16+l15),
// k-range [(s*4+lg)*8, +8). Fragment (g16,s) = 1KB contiguous.
// Candidate-chunk ch (64 cands) = g16 in [4ch,4ch+4) = 32KB contiguous.
__global__ __launch_bounds__(256)
void vq_cvt(const float* __restrict__ emb, u16* __restrict__ e16) {
  int o   = blockIdx.x * 256 + threadIdx.x;   // 0 .. NE*32-1
  int g16 = o >> 9;
  int r   = o & 511;
  int s   = r >> 6;
  int l   = r & 63;
  int lg  = l >> 4, l15 = l & 15;
  int c   = g16 * 16 + l15;
  int kc  = s * 4 + lg;
  const float* src = emb + (size_t)c * DDIM + kc * 8;
  float4 v0 = *reinterpret_cast<const float4*>(src);
  float4 v1 = *reinterpret_cast<const float4*>(src + 4);
  u16 ov[8] = {f2bf(v0.x), f2bf(v0.y), f2bf(v0.z), f2bf(v0.w),
               f2bf(v1.x), f2bf(v1.y), f2bf(v1.z), f2bf(v1.w)};
  *reinterpret_cast<bf16x8*>(e16 + (size_t)o * 8) =
      *reinterpret_cast<bf16x8*>(ov);
}

// ---------------- MFMA approx pass + shortlist (R8 schedule) ------------
// 8 waves: wm=wid>>1 (4 x 16-row group), wn=wid&1 (2 x 32-cand half).
// Swapped operands mfma(bfr, af): lane holds 8 cands of z-row l15.
__global__ __launch_bounds__(512, 4)
void vq_mfma(const float* __restrict__ z, const u16* __restrict__ e16,
             const float* __restrict__ arow, const float* __restrict__ cemb,
             unsigned* __restrict__ cnt, int* __restrict__ list) {
  __shared__ u16 Bs[2][64 * DDIM];   // 2 x 32 KB, fragment-major

  const int t    = threadIdx.x;
  const int R0   = blockIdx.x * BM;
  const int lane = t & 63;
  const int wid  = t >> 6;          // 0..7
  const int wm   = wid >> 1;        // 0..3 : 16-row group
  const int wn   = wid & 1;         // 0..1 : 32-cand half
  const int l15  = lane & 15;
  const int lg   = lane >> 4;       // 0..3

  // ---- A fragments: straight from global z, f32 -> bf16, in registers ----
  // af[s] = z-row (R0+wm*16+l15), global k-chunk (s*4+lg)*8..+8
  bf16x8 af[8];
  const int row = R0 + wm * 16 + l15;
  {
    const float* zr = z + (size_t)row * DDIM;
    #pragma unroll
    for (int s = 0; s < 8; ++s) {
      const float* src = zr + (s * 4 + lg) * 8;
      float4 v0 = *reinterpret_cast<const float4*>(src);
      float4 v1 = *reinterpret_cast<const float4*>(src + 4);
      u16 o[8] = {f2bf(v0.x), f2bf(v0.y), f2bf(v0.z), f2bf(v0.w),
                  f2bf(v1.x), f2bf(v1.y), f2bf(v1.z), f2bf(v1.w)};
      af[s] = *reinterpret_cast<bf16x8*>(o);
    }
  }
  const float a_r = arow[row];
  float runmin = 3.4e38f;

  // ---- prologue: DMA chunk 0 -> Bs[0] (32 frag-KB; wave stages 4) ----
  {
    const char* src = (const char*)e16;
    #pragma unroll
    for (int i = 0; i < 4; ++i) {
      int f = wid * 4 + i;
      gload_lds16(src + f * 1024 + lane * 16, (char*)&Bs[0][0] + f * 1024);
    }
  }
  __syncthreads();   // drains prologue DMA

  for (int ch = 0; ch < NCH; ++ch) {
    const int buf = ch & 1;
    const int C0  = ch * 64;

    // ---- issue next chunk's DMA first (whole chunk to land) ----
    if (ch + 1 < NCH) {
      const char* src = (const char*)e16 + (size_t)(ch + 1) * 32768;
      char* dst = (char*)&Bs[buf ^ 1][0];
      #pragma unroll
      for (int i = 0; i < 4; ++i) {
        int f = wid * 4 + i;
        gload_lds16(src + f * 1024 + lane * 16, dst + f * 1024);
      }
    }

    // ---- hoisted epilogue constants (L2 latency hides under MFMAs) ----
    float4 cvv[2];
    #pragma unroll
    for (int ci = 0; ci < 2; ++ci)
      cvv[ci] = *reinterpret_cast<const float4*>(
          &cemb[C0 + wn * 32 + ci * 16 + lg * 4]);

    // ---- compute: contiguous 1KB fragment reads, 16 MFMAs ----
    f32x4 acc[2];
    acc[0] = (f32x4){0.f, 0.f, 0.f, 0.f};
    acc[1] = (f32x4){0.f, 0.f, 0.f, 0.f};

    const u16* Bp = &Bs[buf][0];
    #pragma unroll
    for (int s = 0; s < 8; ++s) {
      // frag (g16_local = wn*2+ci, s): bytes (g16l*8+s)*1024 + lane*16
      bf16x8 bfr[2];
      #pragma unroll
      for (int ci = 0; ci < 2; ++ci)
        bfr[ci] = *reinterpret_cast<const bf16x8*>(
            &Bp[((wn * 2 + ci) * 8 + s) * 512 + lane * 8]);
      #pragma unroll
      for (int ci = 0; ci < 2; ++ci)
        acc[ci] = __builtin_amdgcn_mfma_f32_16x16x32_bf16(
            bfr[ci], af[s], acc[ci], 0, 0, 0);
    }

    // ---- epilogue (R8-verified): lane-local row min, 2 shuffles, appends --
    // lane's z-row = row; lane's cand (ci,r) = C0 + wn*32 + ci*16 + lg*4 + r
    float lm = 3.4e38f;
    #pragma unroll
    for (int ci = 0; ci < 2; ++ci)
      #pragma unroll
      for (int r = 0; r < 4; ++r) {
        float dd = fmaf(-2.0f, acc[ci][r], a_r) + cvv[ci][r];
        lm = fminf(lm, dd);
      }
    float gm = fminf(lm, __shfl_xor(lm, 16, 64));
    gm = fminf(gm, __shfl_xor(gm, 32, 64));
    runmin = fminf(runmin, gm);
    float thr = runmin + MARGIN;
    if (lm <= thr) {
      // u-form test (R5-verified): d<=thr <=> u >= 0.5*(a+c-thr)
      const float h = 0.5f * (a_r - thr);
      #pragma unroll
      for (int ci = 0; ci < 2; ++ci)
        #pragma unroll
        for (int r = 0; r < 4; ++r)
          if (acc[ci][r] >= fmaf(0.5f, cvv[ci][r], h)) {
            int k = C0 + wn * 32 + ci * 16 + lg * 4 + r;
            unsigned p = atomicAdd(&cnt[row], 1u);
            if (p < CAP) list[(size_t)row * CAP + p] = k;
          }
    }

    __syncthreads();   // drains this chunk's reads + next chunk's DMA
  }
}

// ---------------- exact f32 rescore of shortlists -----------------------
__global__ __launch_bounds__(256)
void vq_rescore(const float* __restrict__ z, const float* __restrict__ emb,
                const float* __restrict__ arow, const float* __restrict__ cemb,
                const unsigned* __restrict__ cnt, const int* __restrict__ list,
                int* __restrict__ ws_idx) {
  const int row  = blockIdx.x * 4 + (threadIdx.x >> 6);
  const int lane = threadIdx.x & 63;
  const float a  = arow[row];
  const float4 zv = *reinterpret_cast<const float4*>(
      z + (size_t)row * DDIM + lane * 4);
  unsigned n = cnt[row];
  float bd = 3.4e38f;
  int   bk = 0;

  const bool fullscan = (n == 0 || n > CAP);
  const int  m = fullscan ? NE : (int)n;
  for (int i = 0; i < m; ++i) {
    int k = fullscan ? i : list[(size_t)row * CAP + i];
    const float4 ev = *reinterpret_cast<const float4*>(
        emb + (size_t)k * DDIM + lane * 4);
    float p = zv.x * ev.x;
    p = fmaf(zv.y, ev.y, p);
    p = fmaf(zv.z, ev.z, p);
    p = fmaf(zv.w, ev.w, p);
    #pragma unroll
    for (int off = 1; off < 64; off <<= 1) p += __shfl_xor(p, off, 64);
    float d = fmaf(-2.0f, p, a) + cemb[k];   // exact ref chain
    if (d < bd || (d == bd && k < bk)) { bd = d; bk = k; }
  }
  if (lane == 0) ws_idx[row] = bk;
}

// ---------------- gather + STE + losses ---------------------------------
__global__ __launch_bounds__(256)
void vq_gather(const float* __restrict__ z, const float* __restrict__ emb,
               const int* __restrict__ ws_idx,
               float* __restrict__ out_zq, float* __restrict__ out_idx,
               double* __restrict__ loss_accum) {
  __shared__ float part[4];
  const int t  = threadIdx.x;
  const int R0 = blockIdx.x * 128;
  float lsum = 0.0f;
  for (int rr = 0; rr < 128; ++rr) {
    const int kb = ws_idx[R0 + rr];
    const size_t gi = (size_t)(R0 + rr) * DDIM + t;
    const float zv = z[gi];
    const float qv = emb[(size_t)kb * DDIM + t];
    const float diff = qv - zv;              // z_q - z
    out_zq[gi] = zv + diff;                  // z + (z_q - z) exact chain
    lsum = fmaf(diff, diff, lsum);
  }
  #pragma unroll
  for (int off = 1; off < 64; off <<= 1) lsum += __shfl_xor(lsum, off, 64);
  if ((t & 63) == 0) part[t >> 6] = lsum;
  __syncthreads();
  if (t == 0) {
    float tot = (part[0] + part[1]) + (part[2] + part[3]);
    atomicAdd(loss_accum, (double)tot);
  }
  if (t < 128) out_idx[R0 + t] = (float)ws_idx[R0 + t];
}

// ---------------- scalar losses -----------------------------------------
__global__ void vq_finalize(const double* __restrict__ loss_accum,
                            float* __restrict__ out_losses) {
  double m = *loss_accum / (double)((size_t)NROWS * DDIM);
  out_losses[0] = (float)(0.25 * m);   // loss_commit = BETA * mse
  out_losses[1] = (float)m;            // loss_codebook
}

extern "C" void kernel_launch(void* const* d_in, const int* in_sizes, int n_in,
                              void* d_out, int out_size, void* d_ws, size_t ws_size,
                              hipStream_t stream) {
  const float* z   = (const float*)d_in[0];
  const float* emb = (const float*)d_in[1];
  float* out        = (float*)d_out;
  float* out_zq     = out;                            // [8388608]
  float* out_losses = out + (size_t)NROWS * DDIM;     // [2]
  float* out_idx    = out + (size_t)NROWS * DDIM + 2; // [32768] as f32

  // persistent ws scratch (small)
  double* loss_accum = (double*)d_ws;
  float*  arow   = (float*)((char*)d_ws + 256);
  float*  cemb   = arow + NROWS;
  int*    ws_idx = (int*)(cemb + NE);

  // large scratch carved from d_out's z_q region (fully rewritten each call;
  // vq_gather overwrites after all readers are done => deterministic)
  u16*      e16  = (u16*)d_out;                              // [0, 4MB)
  int*      list = (int*)((char*)d_out + (4 << 20));         // [4MB, 12MB) CAP=64
  unsigned* cnt  = (unsigned*)((char*)d_out + (12 << 20));   // [12MB, +128KB)

  hipMemsetAsync(d_ws, 0, 8, stream);
  hipMemsetAsync(cnt, 0, NROWS * sizeof(unsigned), stream);
  vq_norms<<<(NROWS + NE) / 4, 256, 0, stream>>>(z, emb, arow, cemb);
  vq_cvt<<<NE * 32 / 256, 256, 0, stream>>>(emb, e16);
  vq_mfma<<<NROWS / BM, 512, 0, stream>>>(z, e16, arow, cemb, cnt, list);
  vq_rescore<<<NROWS / 4, 256, 0, stream>>>(z, emb, arow, cemb, cnt, list, ws_idx);
  vq_gather<<<NROWS / 128, 256, 0, stream>>>(z, emb, ws_idx,
                                             out_zq, out_idx, loss_accum);
  vq_finalize<<<1, 1, 0, stream>>>(loss_accum, out_losses);
}